// Round 6
// baseline (238.522 us; speedup 1.0000x reference)
//
#include <hip/hip_runtime.h>

typedef unsigned short u16;
typedef __attribute__((ext_vector_type(8))) short short8;
typedef __attribute__((ext_vector_type(4))) float f32x4;
typedef __attribute__((ext_vector_type(4))) float float4v;
typedef __attribute__((ext_vector_type(4))) unsigned short u16x4;

#define AS1 __attribute__((address_space(1)))
#define AS3 __attribute__((address_space(3)))

// B=2, T=2048, C=1024, H=16, HD=64
#define Tn 2048
#define Cn 1024
#define Hn 16
#define HDn 64

struct FalseT { static constexpr bool value = false; };
struct TrueT  { static constexpr bool value = true;  };

static __device__ __forceinline__ u16 f2bf(float f) {
    unsigned int u = __float_as_uint(f);
    u += 0x7FFFu + ((u >> 16) & 1u);   // round-to-nearest-even
    return (u16)(u >> 16);
}

static __device__ __forceinline__ void ldlds16(const void* g, void* l) {
    __builtin_amdgcn_global_load_lds((const AS1 unsigned int*)g,
                                     (AS3 unsigned int*)l, 16, 0, 0);
}

// ---------------- elementwise f32 -> bf16 ----------------
__global__ void cvt_bf16(const float* __restrict__ in, u16* __restrict__ out, int n4) {
    int i = blockIdx.x * 256 + threadIdx.x;
    if (i >= n4) return;
    float4v v = ((const float4v*)in)[i];
    u16x4 o;
    o.x = f2bf(v.x); o.y = f2bf(v.y); o.z = f2bf(v.z); o.w = f2bf(v.w);
    ((u16x4*)out)[i] = o;
}

// ---------------- transpose + convert: in[R][Cc] f32 -> out[Cc][R] bf16 ----------------
__global__ void transpose_cvt(const float* __restrict__ in, u16* __restrict__ out,
                              int R, int Cc) {
    __shared__ float t[64][65];
    int r0 = blockIdx.y * 64, c0 = blockIdx.x * 64;
    int tx = threadIdx.x & 63, ty = threadIdx.x >> 6;
#pragma unroll
    for (int i = 0; i < 64; i += 4)
        t[ty + i][tx] = in[(long)(r0 + ty + i) * Cc + c0 + tx];
    __syncthreads();
#pragma unroll
    for (int i = 0; i < 64; i += 4)
        out[(long)(c0 + ty + i) * R + r0 + tx] = f2bf(t[tx][ty + i]);
}

// ---------------- V transpose from combined qkv: -> vtb[bh][64][T] (bf16) ----------------
__global__ void transpose_v(const u16* __restrict__ qkv, u16* __restrict__ out) {
    __shared__ u16 t[64][65];
    int bh = blockIdx.y;
    int b = bh >> 4, h = bh & 15;
    int t0 = blockIdx.x * 64;
    const u16* inp = qkv + ((long)b * Tn + t0) * 3072 + 2048 + h * 64;
    u16* outp = out + (long)bh * Tn * HDn;
    int tx = threadIdx.x & 63, ty = threadIdx.x >> 6;
#pragma unroll
    for (int i = 0; i < 64; i += 4)
        t[ty + i][tx] = inp[(long)(ty + i) * 3072 + tx];
    __syncthreads();
#pragma unroll
    for (int i = 0; i < 64; i += 4)
        outp[(long)(ty + i) * Tn + t0 + tx] = t[tx][ty + i];
}

// ---------------- m97-style GEMM: C[M][N] = A[M][K] * Bt[N][K]^T + bias ----------------
// MODE 0: coalesced bf16 out[M][N].  MODE 1: fp32 out[M][N].
template <int MODE>
__global__ __launch_bounds__(256, 2)
void gemm_bt(const u16* __restrict__ A, const u16* __restrict__ Bt,
             const float* __restrict__ bias,
             u16* __restrict__ o16, float* __restrict__ f_out,
             int M, int N, int K) {
    __shared__ __attribute__((aligned(16))) u16 As[128 * 32];
    __shared__ __attribute__((aligned(16))) u16 Bs[128 * 32];
    const int tid = threadIdx.x;
    const int l = tid & 63;
    const int w = tid >> 6;
    const int wm = (w >> 1) * 64, wn = (w & 1) * 64;
    const long m0 = (long)blockIdx.x * 128, n0 = (long)blockIdx.y * 128;
    const int lm = l & 15, g = l >> 4;

    const int sr = tid >> 2;
    const int sc = (tid & 3) ^ ((tid >> 3) & 3);
    const u16* Ag = A + (m0 + sr) * K + sc * 8;
    const u16* Bg = Bt + (n0 + sr) * K + sc * 8;
    u16* Asl = As + tid * 8;
    u16* Bsl = Bs + tid * 8;

    const int x0 = (lm >> 1) & 3;

    f32x4 acc[4][4] = {};

    for (int k0 = 0; k0 < K; k0 += 32) {
        __syncthreads();
        ldlds16(Ag + k0, Asl);
        ldlds16(Ag + (long)64 * K + k0, Asl + 2048);
        ldlds16(Bg + k0, Bsl);
        ldlds16(Bg + (long)64 * K + k0, Bsl + 2048);
        __syncthreads();
        short8 af[4], bf[4];
#pragma unroll
        for (int mt = 0; mt < 4; ++mt)
            af[mt] = *(const short8*)(As + (wm + mt * 16 + lm) * 32 + ((g ^ x0) * 8));
#pragma unroll
        for (int nt = 0; nt < 4; ++nt)
            bf[nt] = *(const short8*)(Bs + (wn + nt * 16 + lm) * 32 + ((g ^ x0) * 8));
#pragma unroll
        for (int mt = 0; mt < 4; ++mt)
#pragma unroll
            for (int nt = 0; nt < 4; ++nt)
                acc[mt][nt] = __builtin_amdgcn_mfma_f32_16x16x32_bf16(
                    af[mt], bf[nt], acc[mt][nt], 0, 0, 0);
    }

    const int r0 = (l >> 4) * 4;
#pragma unroll
    for (int mt = 0; mt < 4; ++mt) {
#pragma unroll
        for (int nt = 0; nt < 4; ++nt) {
            long n = n0 + wn + nt * 16 + lm;
            float bv = bias[n];
#pragma unroll
            for (int r = 0; r < 4; ++r) {
                long m = m0 + wm + mt * 16 + r0 + r;
                float v = acc[mt][nt][r] + bv;
                if (MODE == 0) o16[m * N + n] = f2bf(v);
                else           f_out[m * N + n] = v;
            }
        }
    }
}

// ---------------- flash attention, uniform split-s chunks ----------------
// qkv[b][t][3C] bf16, Vt[bh][64][T] bf16.
// Job = (bh, qt) 64-row q-tile; split into chunks of <=8 s-tiles.
// qt<8: single chunk, direct yb write (LDS cross-wave reduce).
// qt>=8: each chunk atomically adds fp32 partial O and lsum into Oacc/Lacc
// (valid because softmax uses a STATIC shift: partials over disjoint
// s-ranges are additive). combine kernel normalizes.
__global__ __launch_bounds__(256, 4)
void attn(const u16* __restrict__ qkv, const u16* __restrict__ Vt,
          u16* __restrict__ Y, float* __restrict__ Oacc, float* __restrict__ Lacc) {
    __shared__ __attribute__((aligned(16))) u16 S_lds[20480];
    u16* Ps = S_lds + 16384;

    const int bx = blockIdx.x;
    const int bh = bx & 31;
    const int c = 79 - (bx >> 5);          // heavy chunks first, singles last
    int qt, s0, s1;
    bool single;
    if (c < 8) { qt = c; s0 = 0; s1 = qt + 1; single = true; }
    else {
        int d = c - 8, ch;
        if (d < 16)      { qt = 8 + (d >> 1); ch = d & 1; }
        else if (d < 40) { int e = d - 16; qt = 16 + e / 3; ch = e - (qt - 16) * 3; }
        else             { int e = d - 40; qt = 24 + (e >> 2); ch = e & 3; }
        s0 = ch * 8; s1 = min(s0 + 8, qt + 1); single = false;
    }

    const int tid = threadIdx.x, l = tid & 63, w = tid >> 6;
    const int mh = w >> 1, sh = w & 1;
    const int lm = l & 15, g = l >> 4;
    const int lm7 = lm & 7;
    const int mh32 = mh * 32, sh32 = sh * 32, sh4 = sh * 4, g4 = g * 4;
    const int b = bh >> 4, h = bh & 15;

    const u16* Qp = qkv + ((long)b * Tn + qt * 64) * 3072 + h * 64;
    const u16* Kp = qkv + (long)b * Tn * 3072 + 1024 + h * 64;
    const u16* Vp = Vt + (long)bh * HDn * Tn;

    const int srow = tid >> 3;
    const int schunk = (tid & 7) ^ (srow & 7);
    const int soff = srow * 3072 + schunk * 8;

    // Q fragments straight to registers: 2 m-tiles x 2 k-halves
    short8 qa[2][2];
#pragma unroll
    for (int mt = 0; mt < 2; ++mt)
#pragma unroll
        for (int hh = 0; hh < 2; ++hh)
            qa[mt][hh] = *(const short8*)(Qp + (mh32 + mt * 16 + lm) * 3072 + hh * 32 + g * 8);

    // stage first tile (s0)
    {
        const u16* Kt = Kp + (long)s0 * 64 * 3072;
        ldlds16(Kt + soff, S_lds + tid * 8);
        ldlds16(Kt + 32 * 3072 + soff, S_lds + 2048 + tid * 8);
        const u16* Vg = Vp + s0 * 64;
        ldlds16(Vg + srow * Tn + schunk * 8, S_lds + 8192 + tid * 8);
        ldlds16(Vg + (srow + 32) * Tn + schunk * 8, S_lds + 8192 + 2048 + tid * 8);
    }
    __syncthreads();

    f32x4 o_acc[2][4] = {};
    float lsum[2][4] = {};
    const float SC2 = 0.18033688f;   // 0.125 * log2(e)
    const float MSH = -11.541560f;   // -8 * log2(e)

    auto body = [&](const u16* Kc, const u16* Vc, auto diag_c) {
        constexpr bool DIAG = decltype(diag_c)::value;
        f32x4 s_acc[2][2];
#pragma unroll
        for (int mt = 0; mt < 2; ++mt)
#pragma unroll
            for (int nt = 0; nt < 2; ++nt)
                s_acc[mt][nt] = (f32x4){0.f, 0.f, 0.f, 0.f};
#pragma unroll
        for (int nt = 0; nt < 2; ++nt)
#pragma unroll
            for (int hh = 0; hh < 2; ++hh) {
                short8 kf = *(const short8*)(Kc + (sh32 + nt * 16 + lm) * 64 +
                                             (((hh * 4 + g) ^ lm7) * 8));
                s_acc[0][nt] = __builtin_amdgcn_mfma_f32_16x16x32_bf16(qa[0][hh], kf, s_acc[0][nt], 0, 0, 0);
                s_acc[1][nt] = __builtin_amdgcn_mfma_f32_16x16x32_bf16(qa[1][hh], kf, s_acc[1][nt], 0, 0, 0);
            }
#pragma unroll
        for (int mt = 0; mt < 2; ++mt)
#pragma unroll
            for (int nt = 0; nt < 2; ++nt) {
                int scol = sh32 + nt * 16 + lm;
#pragma unroll
                for (int r = 0; r < 4; ++r) {
                    float x = fmaf(s_acc[mt][nt][r], SC2, MSH);
                    if (DIAG && scol > mh32 + mt * 16 + g4 + r) x = -1e30f;
                    float p = exp2f(x);
                    lsum[mt][r] += p;
                    int prow = mh32 + mt * 16 + g4 + r;
                    int cc = sh4 + nt * 2 + (lm >> 3);
                    Ps[prow * 64 + ((cc ^ (prow & 7)) * 8) + lm7] = f2bf(p);
                }
            }
        asm volatile("s_waitcnt lgkmcnt(0)" ::: "memory");

        short8 pf0 = *(const short8*)(Ps + (mh32 + lm) * 64 + (((sh4 + g) ^ lm7) * 8));
        short8 pf1 = *(const short8*)(Ps + (mh32 + 16 + lm) * 64 + (((sh4 + g) ^ lm7) * 8));
#pragma unroll
        for (int dt = 0; dt < 4; ++dt) {
            short8 vf = *(const short8*)(Vc + (dt * 16 + lm) * 64 + (((sh4 + g) ^ lm7) * 8));
            o_acc[0][dt] = __builtin_amdgcn_mfma_f32_16x16x32_bf16(pf0, vf, o_acc[0][dt], 0, 0, 0);
            o_acc[1][dt] = __builtin_amdgcn_mfma_f32_16x16x32_bf16(pf1, vf, o_acc[1][dt], 0, 0, 0);
        }
    };

    const int last = s1 - 1;
    for (int st = s0; st < last; ++st) {
        const int cur = (st - s0) & 1;
        if (st > s0) __syncthreads();
        {   // prefetch st+1
            u16* Kn = S_lds + (cur ^ 1) * 4096;
            u16* Vn = S_lds + 8192 + (cur ^ 1) * 4096;
            const u16* Kt = Kp + (long)(st + 1) * 64 * 3072;
            ldlds16(Kt + soff, Kn + tid * 8);
            ldlds16(Kt + 32 * 3072 + soff, Kn + 2048 + tid * 8);
            const u16* Vg = Vp + (st + 1) * 64;
            ldlds16(Vg + srow * Tn + schunk * 8, Vn + tid * 8);
            ldlds16(Vg + (srow + 32) * Tn + schunk * 8, Vn + 2048 + tid * 8);
        }
        body(S_lds + cur * 4096, S_lds + 8192 + cur * 4096, FalseT{});
    }
    if (last > s0) __syncthreads();
    {
        const int cur = (last - s0) & 1;
        if (last == qt) body(S_lds + cur * 4096, S_lds + 8192 + cur * 4096, TrueT{});
        else            body(S_lds + cur * 4096, S_lds + 8192 + cur * 4096, FalseT{});
    }

    // lsum: reduce over the 16 lanes of each row group (both paths need it)
#pragma unroll
    for (int mt = 0; mt < 2; ++mt)
#pragma unroll
        for (int r = 0; r < 4; ++r) {
#pragma unroll
            for (int off = 1; off < 16; off <<= 1)
                lsum[mt][r] += __shfl_xor(lsum[mt][r], off, 64);
        }

    if (!single) {
        // atomic fp32 partial accumulation (additive thanks to static shift)
        const long rbase = ((long)bh * 24 + (qt - 8)) * 64;
#pragma unroll
        for (int mt = 0; mt < 2; ++mt) {
#pragma unroll
            for (int dt = 0; dt < 4; ++dt)
#pragma unroll
                for (int r = 0; r < 4; ++r)
                    unsafeAtomicAdd(&Oacc[(rbase + mh32 + mt * 16 + g4 + r) * 64 + dt * 16 + lm],
                                    o_acc[mt][dt][r]);
            if (lm == 0)
#pragma unroll
                for (int r = 0; r < 4; ++r)
                    unsafeAtomicAdd(&Lacc[rbase + mh32 + mt * 16 + g4 + r], lsum[mt][r]);
        }
        return;
    }

    // single-chunk: cross-sh reduce in LDS, normalize, direct yb write
    __syncthreads();
    f32x4* redv = (f32x4*)S_lds;
    float* redl = (float*)(S_lds + 8192);

    if (sh == 1) {
#pragma unroll
        for (int mt = 0; mt < 2; ++mt)
#pragma unroll
            for (int dt = 0; dt < 4; ++dt)
                redv[(mh * 64 + l) * 8 + mt * 4 + dt] = o_acc[mt][dt];
#pragma unroll
        for (int mt = 0; mt < 2; ++mt)
#pragma unroll
            for (int r = 0; r < 4; ++r)
                if (lm == mt * 4 + r)
                    redl[mh32 + mt * 16 + g4 + r] = lsum[mt][r];
    }
    __syncthreads();
    if (sh == 0) {
#pragma unroll
        for (int mt = 0; mt < 2; ++mt) {
#pragma unroll
            for (int dt = 0; dt < 4; ++dt)
                o_acc[mt][dt] += redv[(mh * 64 + l) * 8 + mt * 4 + dt];
#pragma unroll
            for (int r = 0; r < 4; ++r) {
                float total = lsum[mt][r] + redl[mh32 + mt * 16 + g4 + r];
                float inv = 1.0f / total;
                int t = qt * 64 + mh32 + mt * 16 + g4 + r;
                long base = ((long)b * Tn + t) * Cn + h * HDn;
#pragma unroll
                for (int dt = 0; dt < 4; ++dt)
                    Y[base + dt * 16 + lm] = f2bf(o_acc[mt][dt][r] * inv);
            }
        }
    }
}

// ---------------- combine: normalize split-job partials -> yb bf16 ----------------
__global__ void combine(const float* __restrict__ Oacc, const float* __restrict__ Lacc,
                        u16* __restrict__ Y) {
    int e4 = blockIdx.x * 256 + threadIdx.x;        // one float4 each
    int row = e4 >> 4;                              // (bh*24 + qt-8)*64 + r
    int dq = e4 & 15;
    float4v v = ((const float4v*)Oacc)[e4];
    float inv = 1.0f / Lacc[row];
    int bh = row / 1536;
    int rr = row - bh * 1536;
    int qtm8 = rr >> 6, r = rr & 63;
    int b = bh >> 4, h = bh & 15;
    int t = (qtm8 + 8) * 64 + r;
    long base = ((long)b * Tn + t) * Cn + h * HDn + dq * 4;
    u16x4 o;
    o.x = f2bf(v.x * inv); o.y = f2bf(v.y * inv);
    o.z = f2bf(v.z * inv); o.w = f2bf(v.w * inv);
    *(u16x4*)(Y + base) = o;
}

extern "C" void kernel_launch(void* const* d_in, const int* in_sizes, int n_in,
                              void* d_out, int out_size, void* d_ws, size_t ws_size,
                              hipStream_t stream) {
    const float* x    = (const float*)d_in[0];
    const float* Wqkv = (const float*)d_in[1];
    const float* bqkv = (const float*)d_in[2];
    const float* Wo   = (const float*)d_in[3];
    const float* bo   = (const float*)d_in[4];
    float* out = (float*)d_out;

    u16* xb    = (u16*)d_ws;          // 4M u16 : x bf16            [dead after gemm0]
    u16* wqkvt = xb + 4194304;        // 3M : Wqkv^T                [dead after gemm0]
    u16* wot   = wqkvt + 3145728;     // 1M : Wo^T
    u16* qkvb  = wot + 1048576;       // 12M : qkv [b,t,3C] bf16
    u16* vtb   = qkvb + 12582912;     // 4M : V^T [b,h,d,t]
    u16* yb    = vtb + 4194304;       // 4M : attn out [b,t,c]
    // fp32 accumulators overlay the dead xb+wqkvt region (14.68 MB >= 12.78 MB)
    float* Oacc = (float*)d_ws;             // 32bh * 24qt * 64r * 64d
    float* Lacc = Oacc + 3145728;           // 32bh * 24qt * 64r

    cvt_bf16<<<4096, 256, 0, stream>>>(x, xb, 1048576);
    transpose_cvt<<<dim3(48, 16), 256, 0, stream>>>(Wqkv, wqkvt, 1024, 3072);
    transpose_cvt<<<dim3(16, 16), 256, 0, stream>>>(Wo, wot, 1024, 1024);
    gemm_bt<0><<<dim3(32, 24), 256, 0, stream>>>(xb, wqkvt, bqkv, qkvb, nullptr,
                                                 4096, 3072, 1024);
    hipMemsetAsync(d_ws, 0, 12779520, stream);   // zero Oacc+Lacc (xb/wqkvt dead)
    transpose_v<<<dim3(32, 32), 256, 0, stream>>>(qkvb, vtb);
    attn<<<2560, 256, 0, stream>>>(qkvb, vtb, yb, Oacc, Lacc);
    combine<<<3072, 256, 0, stream>>>(Oacc, Lacc, yb);
    gemm_bt<1><<<dim3(32, 8), 256, 0, stream>>>(yb, wot, bo, nullptr, out,
                                                4096, 1024, 1024);
}

// Round 7
// 209.575 us; speedup vs baseline: 1.1381x; 1.1381x over previous
//
#include <hip/hip_runtime.h>

typedef unsigned short u16;
typedef __attribute__((ext_vector_type(8))) short short8;
typedef __attribute__((ext_vector_type(4))) float f32x4;
typedef __attribute__((ext_vector_type(4))) float float4v;
typedef __attribute__((ext_vector_type(4))) unsigned short u16x4;

#define AS1 __attribute__((address_space(1)))
#define AS3 __attribute__((address_space(3)))

// B=2, T=2048, C=1024, H=16, HD=64
#define Tn 2048
#define Cn 1024
#define Hn 16
#define HDn 64

struct FalseT { static constexpr bool value = false; };
struct TrueT  { static constexpr bool value = true;  };

static __device__ __forceinline__ u16 f2bf(float f) {
    unsigned int u = __float_as_uint(f);
    u += 0x7FFFu + ((u >> 16) & 1u);   // round-to-nearest-even
    return (u16)(u >> 16);
}

static __device__ __forceinline__ void ldlds16(const void* g, void* l) {
    __builtin_amdgcn_global_load_lds((const AS1 unsigned int*)g,
                                     (AS3 unsigned int*)l, 16, 0, 0);
}

// ---------------- elementwise f32 -> bf16 ----------------
__global__ void cvt_bf16(const float* __restrict__ in, u16* __restrict__ out, int n4) {
    int i = blockIdx.x * 256 + threadIdx.x;
    if (i >= n4) return;
    float4v v = ((const float4v*)in)[i];
    u16x4 o;
    o.x = f2bf(v.x); o.y = f2bf(v.y); o.z = f2bf(v.z); o.w = f2bf(v.w);
    ((u16x4*)out)[i] = o;
}

// ---------------- transpose + convert: in[R][Cc] f32 -> out[Cc][R] bf16 ----------------
__global__ void transpose_cvt(const float* __restrict__ in, u16* __restrict__ out,
                              int R, int Cc) {
    __shared__ float t[64][65];
    int r0 = blockIdx.y * 64, c0 = blockIdx.x * 64;
    int tx = threadIdx.x & 63, ty = threadIdx.x >> 6;
#pragma unroll
    for (int i = 0; i < 64; i += 4)
        t[ty + i][tx] = in[(long)(r0 + ty + i) * Cc + c0 + tx];
    __syncthreads();
#pragma unroll
    for (int i = 0; i < 64; i += 4)
        out[(long)(c0 + ty + i) * R + r0 + tx] = f2bf(t[tx][ty + i]);
}

// ---------------- V transpose from combined qkv: -> vtb[bh][64][T] (bf16) ----------------
__global__ void transpose_v(const u16* __restrict__ qkv, u16* __restrict__ out) {
    __shared__ u16 t[64][65];
    int bh = blockIdx.y;
    int b = bh >> 4, h = bh & 15;
    int t0 = blockIdx.x * 64;
    const u16* inp = qkv + ((long)b * Tn + t0) * 3072 + 2048 + h * 64;
    u16* outp = out + (long)bh * Tn * HDn;
    int tx = threadIdx.x & 63, ty = threadIdx.x >> 6;
#pragma unroll
    for (int i = 0; i < 64; i += 4)
        t[ty + i][tx] = inp[(long)(ty + i) * 3072 + tx];
    __syncthreads();
#pragma unroll
    for (int i = 0; i < 64; i += 4)
        outp[(long)(ty + i) * Tn + t0 + tx] = t[tx][ty + i];
}

// ---------------- m97-style GEMM: C[M][N] = A[M][K] * Bt[N][K]^T + bias ----------------
// MODE 0: coalesced bf16 out[M][N].  MODE 1: fp32 out[M][N].
template <int MODE>
__global__ __launch_bounds__(256, 2)
void gemm_bt(const u16* __restrict__ A, const u16* __restrict__ Bt,
             const float* __restrict__ bias,
             u16* __restrict__ o16, float* __restrict__ f_out,
             int M, int N, int K) {
    __shared__ __attribute__((aligned(16))) u16 As[128 * 32];
    __shared__ __attribute__((aligned(16))) u16 Bs[128 * 32];
    const int tid = threadIdx.x;
    const int l = tid & 63;
    const int w = tid >> 6;
    const int wm = (w >> 1) * 64, wn = (w & 1) * 64;
    const long m0 = (long)blockIdx.x * 128, n0 = (long)blockIdx.y * 128;
    const int lm = l & 15, g = l >> 4;

    const int sr = tid >> 2;
    const int sc = (tid & 3) ^ ((tid >> 3) & 3);
    const u16* Ag = A + (m0 + sr) * K + sc * 8;
    const u16* Bg = Bt + (n0 + sr) * K + sc * 8;
    u16* Asl = As + tid * 8;
    u16* Bsl = Bs + tid * 8;

    const int x0 = (lm >> 1) & 3;

    f32x4 acc[4][4] = {};

    for (int k0 = 0; k0 < K; k0 += 32) {
        __syncthreads();
        ldlds16(Ag + k0, Asl);
        ldlds16(Ag + (long)64 * K + k0, Asl + 2048);
        ldlds16(Bg + k0, Bsl);
        ldlds16(Bg + (long)64 * K + k0, Bsl + 2048);
        __syncthreads();
        short8 af[4], bf[4];
#pragma unroll
        for (int mt = 0; mt < 4; ++mt)
            af[mt] = *(const short8*)(As + (wm + mt * 16 + lm) * 32 + ((g ^ x0) * 8));
#pragma unroll
        for (int nt = 0; nt < 4; ++nt)
            bf[nt] = *(const short8*)(Bs + (wn + nt * 16 + lm) * 32 + ((g ^ x0) * 8));
#pragma unroll
        for (int mt = 0; mt < 4; ++mt)
#pragma unroll
            for (int nt = 0; nt < 4; ++nt)
                acc[mt][nt] = __builtin_amdgcn_mfma_f32_16x16x32_bf16(
                    af[mt], bf[nt], acc[mt][nt], 0, 0, 0);
    }

    const int r0 = (l >> 4) * 4;
#pragma unroll
    for (int mt = 0; mt < 4; ++mt) {
#pragma unroll
        for (int nt = 0; nt < 4; ++nt) {
            long n = n0 + wn + nt * 16 + lm;
            float bv = bias[n];
#pragma unroll
            for (int r = 0; r < 4; ++r) {
                long m = m0 + wm + mt * 16 + r0 + r;
                float v = acc[mt][nt][r] + bv;
                if (MODE == 0) o16[m * N + n] = f2bf(v);
                else           f_out[m * N + n] = v;
            }
        }
    }
}

// ---------------- flash attention, 2x2 wave split, hoisted P addressing ----------------
// qkv[b][t][3C] bf16, Vt[bh][64][T] bf16 -> Y[b][t][c] bf16.
// Static-shift softmax (additive partials, no running max).
// P-store swizzle chunk^=((prow>>2)&3)<<1 == g<<1: r-invariant -> all 16 store
// addresses are loop-invariant VGPR bases + ds-offset immediates (r*128).
// P stored via truncating bf16 (p>=0; rel err 2^-8, inside threshold).
// K-loop unrolled x2 so double-buffer parity is compile-time.
__global__ __launch_bounds__(256, 4)
void attn(const u16* __restrict__ qkv, const u16* __restrict__ Vt,
          u16* __restrict__ Y) {
    __shared__ __attribute__((aligned(16))) u16 S_lds[20480];
    u16* Ps = S_lds + 16384;

    const int bh = blockIdx.y;
    const int qt = 31 - (int)blockIdx.x;   // heavy tiles first
    const int tid = threadIdx.x, l = tid & 63, w = tid >> 6;
    const int mh = w >> 1, sh = w & 1;
    const int lm = l & 15, g = l >> 4;
    const int lm7 = lm & 7;
    const int mh32 = mh * 32, sh32 = sh * 32, sh4 = sh * 4, g4 = g * 4;
    const int b = bh >> 4, h = bh & 15;

    const u16* Qp = qkv + ((long)b * Tn + qt * 64) * 3072 + h * 64;
    const u16* Kp = qkv + (long)b * Tn * 3072 + 1024 + h * 64;
    const u16* Vp = Vt + (long)bh * HDn * Tn;

    const int srow = tid >> 3;
    const int schunk = (tid & 7) ^ (srow & 7);
    const int soff = srow * 3072 + schunk * 8;

    // Q fragments straight to registers: 2 m-tiles x 2 k-halves
    short8 qa[2][2];
#pragma unroll
    for (int mt = 0; mt < 2; ++mt)
#pragma unroll
        for (int hh = 0; hh < 2; ++hh)
            qa[mt][hh] = *(const short8*)(Qp + (mh32 + mt * 16 + lm) * 3072 + hh * 32 + g * 8);

    // loop-invariant P-store bases (r enters as ds-offset r*128B)
    u16* pw[2][2];
#pragma unroll
    for (int mt = 0; mt < 2; ++mt)
#pragma unroll
        for (int nt = 0; nt < 2; ++nt)
            pw[mt][nt] = Ps + (mh32 + mt * 16 + g4) * 64 +
                         (((sh4 + nt * 2 + (lm >> 3)) ^ (g << 1)) * 8) + lm7;
    // loop-invariant P-read addresses (A-frag), matching swizzle ((row>>2)&3)<<1
    const int prsw = ((sh4 + g) ^ (((lm >> 2) & 3) << 1)) * 8;
    const u16* pr0 = Ps + (mh32 + lm) * 64 + prsw;
    const u16* pr1 = Ps + (mh32 + 16 + lm) * 64 + prsw;

    // stage tile 0 -> buf0
    ldlds16(Kp + soff, S_lds + tid * 8);
    ldlds16(Kp + 32 * 3072 + soff, S_lds + 2048 + tid * 8);
    ldlds16(Vp + srow * Tn + schunk * 8, S_lds + 8192 + tid * 8);
    ldlds16(Vp + (srow + 32) * Tn + schunk * 8, S_lds + 8192 + 2048 + tid * 8);
    __syncthreads();

    f32x4 o_acc[2][4] = {};
    float lsum[2][4] = {};
    const float SC2 = 0.18033688f;   // 0.125 * log2(e)
    const float MSH = -11.541560f;   // -8 * log2(e)

    auto prefetch = [&](int st, int buf) {
        u16* Kn = S_lds + buf * 4096;
        u16* Vn = S_lds + 8192 + buf * 4096;
        const u16* Kt = Kp + (long)st * 64 * 3072;
        ldlds16(Kt + soff, Kn + tid * 8);
        ldlds16(Kt + 32 * 3072 + soff, Kn + 2048 + tid * 8);
        const u16* Vg = Vp + st * 64;
        ldlds16(Vg + srow * Tn + schunk * 8, Vn + tid * 8);
        ldlds16(Vg + (srow + 32) * Tn + schunk * 8, Vn + 2048 + tid * 8);
    };

    auto body = [&](int buf, auto diag_c) {
        constexpr bool DIAG = decltype(diag_c)::value;
        const u16* Kc = S_lds + buf * 4096;
        const u16* Vc = S_lds + 8192 + buf * 4096;
        f32x4 s_acc[2][2];
#pragma unroll
        for (int mt = 0; mt < 2; ++mt)
#pragma unroll
            for (int nt = 0; nt < 2; ++nt)
                s_acc[mt][nt] = (f32x4){0.f, 0.f, 0.f, 0.f};
#pragma unroll
        for (int nt = 0; nt < 2; ++nt)
#pragma unroll
            for (int hh = 0; hh < 2; ++hh) {
                short8 kf = *(const short8*)(Kc + (sh32 + nt * 16 + lm) * 64 +
                                             (((hh * 4 + g) ^ lm7) * 8));
                s_acc[0][nt] = __builtin_amdgcn_mfma_f32_16x16x32_bf16(qa[0][hh], kf, s_acc[0][nt], 0, 0, 0);
                s_acc[1][nt] = __builtin_amdgcn_mfma_f32_16x16x32_bf16(qa[1][hh], kf, s_acc[1][nt], 0, 0, 0);
            }
#pragma unroll
        for (int mt = 0; mt < 2; ++mt)
#pragma unroll
            for (int nt = 0; nt < 2; ++nt) {
                int scol = sh32 + nt * 16 + lm;
#pragma unroll
                for (int r = 0; r < 4; ++r) {
                    float x = fmaf(s_acc[mt][nt][r], SC2, MSH);
                    if (DIAG && scol > mh32 + mt * 16 + g4 + r) x = -1e30f;
                    float p = exp2f(x);
                    lsum[mt][r] += p;
                    pw[mt][nt][r * 64] = (u16)(__float_as_uint(p) >> 16);  // trunc bf16
                }
            }
        asm volatile("s_waitcnt lgkmcnt(0)" ::: "memory");

        short8 pf0 = *(const short8*)pr0;
        short8 pf1 = *(const short8*)pr1;
#pragma unroll
        for (int dt = 0; dt < 4; ++dt) {
            short8 vf = *(const short8*)(Vc + (dt * 16 + lm) * 64 + (((sh4 + g) ^ lm7) * 8));
            o_acc[0][dt] = __builtin_amdgcn_mfma_f32_16x16x32_bf16(pf0, vf, o_acc[0][dt], 0, 0, 0);
            o_acc[1][dt] = __builtin_amdgcn_mfma_f32_16x16x32_bf16(pf1, vf, o_acc[1][dt], 0, 0, 0);
        }
    };

    // unrolled x2 K-loop: tile k lives in buf (k&1); compile-time parity
    int st = 0;
    for (; st + 2 <= qt; st += 2) {
        prefetch(st + 1, 1); body(0, FalseT{}); __syncthreads();
        prefetch(st + 2, 0); body(1, FalseT{}); __syncthreads();
    }
    if (st < qt) {           // st == qt-1 (even), qt odd
        prefetch(qt, 1); body(0, FalseT{}); __syncthreads();
        body(1, TrueT{});
    } else {                 // st == qt (even)
        body(0, TrueT{});
    }

    // lsum: reduce over the 16 lanes of each row group
#pragma unroll
    for (int mt = 0; mt < 2; ++mt)
#pragma unroll
        for (int r = 0; r < 4; ++r) {
#pragma unroll
            for (int off = 1; off < 16; off <<= 1)
                lsum[mt][r] += __shfl_xor(lsum[mt][r], off, 64);
        }

    // cross-sh reduce in LDS, normalize, write Y
    __syncthreads();
    f32x4* redv = (f32x4*)S_lds;
    float* redl = (float*)(S_lds + 8192);

    if (sh == 1) {
#pragma unroll
        for (int mt = 0; mt < 2; ++mt)
#pragma unroll
            for (int dt = 0; dt < 4; ++dt)
                redv[(mh * 64 + l) * 8 + mt * 4 + dt] = o_acc[mt][dt];
#pragma unroll
        for (int mt = 0; mt < 2; ++mt)
#pragma unroll
            for (int r = 0; r < 4; ++r)
                if (lm == mt * 4 + r)
                    redl[mh32 + mt * 16 + g4 + r] = lsum[mt][r];
    }
    __syncthreads();
    if (sh == 0) {
#pragma unroll
        for (int mt = 0; mt < 2; ++mt) {
#pragma unroll
            for (int dt = 0; dt < 4; ++dt)
                o_acc[mt][dt] += redv[(mh * 64 + l) * 8 + mt * 4 + dt];
#pragma unroll
            for (int r = 0; r < 4; ++r) {
                float total = lsum[mt][r] + redl[mh32 + mt * 16 + g4 + r];
                float inv = 1.0f / total;
                int t = qt * 64 + mh32 + mt * 16 + g4 + r;
                long base = ((long)b * Tn + t) * Cn + h * HDn;
#pragma unroll
                for (int dt = 0; dt < 4; ++dt)
                    Y[base + dt * 16 + lm] = f2bf(o_acc[mt][dt][r] * inv);
            }
        }
    }
}

extern "C" void kernel_launch(void* const* d_in, const int* in_sizes, int n_in,
                              void* d_out, int out_size, void* d_ws, size_t ws_size,
                              hipStream_t stream) {
    const float* x    = (const float*)d_in[0];
    const float* Wqkv = (const float*)d_in[1];
    const float* bqkv = (const float*)d_in[2];
    const float* Wo   = (const float*)d_in[3];
    const float* bo   = (const float*)d_in[4];
    float* out = (float*)d_out;

    u16* xb    = (u16*)d_ws;          // 4M u16 : x bf16
    u16* wqkvt = xb + 4194304;        // 3M : Wqkv^T
    u16* wot   = wqkvt + 3145728;     // 1M : Wo^T
    u16* qkvb  = wot + 1048576;       // 12M : qkv [b,t,3C] bf16
    u16* vtb   = qkvb + 12582912;     // 4M : V^T [b,h,d,t]
    u16* yb    = vtb + 4194304;       // 4M : attn out [b,t,c]

    cvt_bf16<<<4096, 256, 0, stream>>>(x, xb, 1048576);
    transpose_cvt<<<dim3(48, 16), 256, 0, stream>>>(Wqkv, wqkvt, 1024, 3072);
    transpose_cvt<<<dim3(16, 16), 256, 0, stream>>>(Wo, wot, 1024, 1024);
    gemm_bt<0><<<dim3(32, 24), 256, 0, stream>>>(xb, wqkvt, bqkv, qkvb, nullptr,
                                                 4096, 3072, 1024);
    transpose_v<<<dim3(32, 32), 256, 0, stream>>>(qkvb, vtb);
    attn<<<dim3(32, 32), 256, 0, stream>>>(qkvb, vtb, yb);
    gemm_bt<1><<<dim3(32, 8), 256, 0, stream>>>(yb, wot, bo, nullptr, out,
                                                4096, 1024, 1024);
}

// Round 8
// 192.742 us; speedup vs baseline: 1.2375x; 1.0873x over previous
//
#include <hip/hip_runtime.h>

typedef unsigned short u16;
typedef __attribute__((ext_vector_type(8))) short short8;
typedef __attribute__((ext_vector_type(4))) float f32x4;
typedef __attribute__((ext_vector_type(4))) float float4v;
typedef __attribute__((ext_vector_type(4))) unsigned short u16x4;

#define AS1 __attribute__((address_space(1)))
#define AS3 __attribute__((address_space(3)))

// B=2, T=2048, C=1024, H=16, HD=64
#define Tn 2048
#define Cn 1024
#define Hn 16
#define HDn 64

struct FalseT { static constexpr bool value = false; };
struct TrueT  { static constexpr bool value = true;  };

static __device__ __forceinline__ u16 f2bf(float f) {
    unsigned int u = __float_as_uint(f);
    u += 0x7FFFu + ((u >> 16) & 1u);   // round-to-nearest-even
    return (u16)(u >> 16);
}

static __device__ __forceinline__ void ldlds16(const void* g, void* l) {
    __builtin_amdgcn_global_load_lds((const AS1 unsigned int*)g,
                                     (AS3 unsigned int*)l, 16, 0, 0);
}

// ---------------- elementwise f32 -> bf16 ----------------
__global__ void cvt_bf16(const float* __restrict__ in, u16* __restrict__ out, int n4) {
    int i = blockIdx.x * 256 + threadIdx.x;
    if (i >= n4) return;
    float4v v = ((const float4v*)in)[i];
    u16x4 o;
    o.x = f2bf(v.x); o.y = f2bf(v.y); o.z = f2bf(v.z); o.w = f2bf(v.w);
    ((u16x4*)out)[i] = o;
}

// ---------------- transpose + convert: in[R][Cc] f32 -> out[Cc][R] bf16 ----------------
__global__ void transpose_cvt(const float* __restrict__ in, u16* __restrict__ out,
                              int R, int Cc) {
    __shared__ float t[64][65];
    int r0 = blockIdx.y * 64, c0 = blockIdx.x * 64;
    int tx = threadIdx.x & 63, ty = threadIdx.x >> 6;
#pragma unroll
    for (int i = 0; i < 64; i += 4)
        t[ty + i][tx] = in[(long)(r0 + ty + i) * Cc + c0 + tx];
    __syncthreads();
#pragma unroll
    for (int i = 0; i < 64; i += 4)
        out[(long)(c0 + ty + i) * R + r0 + tx] = f2bf(t[tx][ty + i]);
}

// ---------------- V transpose from combined qkv: -> vtb[bh][64][T] (bf16) ----------------
__global__ void transpose_v(const u16* __restrict__ qkv, u16* __restrict__ out) {
    __shared__ u16 t[64][65];
    int bh = blockIdx.y;
    int b = bh >> 4, h = bh & 15;
    int t0 = blockIdx.x * 64;
    const u16* inp = qkv + ((long)b * Tn + t0) * 3072 + 2048 + h * 64;
    u16* outp = out + (long)bh * Tn * HDn;
    int tx = threadIdx.x & 63, ty = threadIdx.x >> 6;
#pragma unroll
    for (int i = 0; i < 64; i += 4)
        t[ty + i][tx] = inp[(long)(ty + i) * 3072 + tx];
    __syncthreads();
#pragma unroll
    for (int i = 0; i < 64; i += 4)
        outp[(long)(ty + i) * Tn + t0 + tx] = t[tx][ty + i];
}

// ---------------- m97-style GEMM: C[M][N] = A[M][K] * Bt[N][K]^T + bias ----------------
// MODE 0: coalesced bf16 out[M][N].  MODE 1: fp32 out[M][N].
template <int MODE>
__global__ __launch_bounds__(256, 2)
void gemm_bt(const u16* __restrict__ A, const u16* __restrict__ Bt,
             const float* __restrict__ bias,
             u16* __restrict__ o16, float* __restrict__ f_out,
             int M, int N, int K) {
    __shared__ __attribute__((aligned(16))) u16 As[128 * 32];
    __shared__ __attribute__((aligned(16))) u16 Bs[128 * 32];
    const int tid = threadIdx.x;
    const int l = tid & 63;
    const int w = tid >> 6;
    const int wm = (w >> 1) * 64, wn = (w & 1) * 64;
    const long m0 = (long)blockIdx.x * 128, n0 = (long)blockIdx.y * 128;
    const int lm = l & 15, g = l >> 4;

    const int sr = tid >> 2;
    const int sc = (tid & 3) ^ ((tid >> 3) & 3);
    const u16* Ag = A + (m0 + sr) * K + sc * 8;
    const u16* Bg = Bt + (n0 + sr) * K + sc * 8;
    u16* Asl = As + tid * 8;
    u16* Bsl = Bs + tid * 8;

    const int x0 = (lm >> 1) & 3;

    f32x4 acc[4][4] = {};

    for (int k0 = 0; k0 < K; k0 += 32) {
        __syncthreads();
        ldlds16(Ag + k0, Asl);
        ldlds16(Ag + (long)64 * K + k0, Asl + 2048);
        ldlds16(Bg + k0, Bsl);
        ldlds16(Bg + (long)64 * K + k0, Bsl + 2048);
        __syncthreads();
        short8 af[4], bf[4];
#pragma unroll
        for (int mt = 0; mt < 4; ++mt)
            af[mt] = *(const short8*)(As + (wm + mt * 16 + lm) * 32 + ((g ^ x0) * 8));
#pragma unroll
        for (int nt = 0; nt < 4; ++nt)
            bf[nt] = *(const short8*)(Bs + (wn + nt * 16 + lm) * 32 + ((g ^ x0) * 8));
#pragma unroll
        for (int mt = 0; mt < 4; ++mt)
#pragma unroll
            for (int nt = 0; nt < 4; ++nt)
                acc[mt][nt] = __builtin_amdgcn_mfma_f32_16x16x32_bf16(
                    af[mt], bf[nt], acc[mt][nt], 0, 0, 0);
    }

    const int r0 = (l >> 4) * 4;
#pragma unroll
    for (int mt = 0; mt < 4; ++mt) {
#pragma unroll
        for (int nt = 0; nt < 4; ++nt) {
            long n = n0 + wn + nt * 16 + lm;
            float bv = bias[n];
#pragma unroll
            for (int r = 0; r < 4; ++r) {
                long m = m0 + wm + mt * 16 + r0 + r;
                float v = acc[mt][nt][r] + bv;
                if (MODE == 0) o16[m * N + n] = f2bf(v);
                else           f_out[m * N + n] = v;
            }
        }
    }
}

// ---------------- flash attention: paired jobs + 128-col s-tiles ----------------
// qkv[b][t][3C] bf16, Vt[bh][64][T] bf16 -> Y[b][t][c] bf16.
// Block x in [0,16) runs jobs qt=31-x then qt=x: exactly 33 s-tiles per block
// regardless of dispatch mapping (perfect balance).
// Iteration = 128 s-cols (2 tiles): half the barriers, 32 MFMA/wave-iter.
// Static-shift softmax; final iteration masks scol>qrow over all 128 cols,
// which also nulls the out-of-range tile when qt is even.
// LDS 80 KB: Ks[2] 128x64 @0/8192, Vs[2] 64x128 @16384/24576, Ps 64x128 @32768.
__global__ __launch_bounds__(256, 2)
void attn(const u16* __restrict__ qkv, const u16* __restrict__ Vt,
          u16* __restrict__ Y) {
    __shared__ __attribute__((aligned(16))) u16 S_lds[40960];
    u16* Ps = S_lds + 32768;

    const int bh = blockIdx.y;
    const int px = blockIdx.x;             // 0..15
    const int tid = threadIdx.x, l = tid & 63, w = tid >> 6;
    const int mh = w >> 1, sh = w & 1;
    const int lm = l & 15, g = l >> 4;
    const int lm7 = lm & 7;
    const int mh32 = mh * 32, sh64 = sh * 64, sh8 = sh * 8, g4 = g * 4;
    const int b = bh >> 4, h = bh & 15;

    const u16* Kp = qkv + (long)b * Tn * 3072 + 1024 + h * 64;
    const u16* Vp = Vt + (long)bh * HDn * Tn;

    // staging offsets (per-thread, fixed)
    const int soffK = (tid >> 3) * 3072 + (((tid & 7) ^ ((tid >> 3) & 7)) * 8);
    const int soffV = (tid >> 4) * Tn + ((((tid & 15) ^ (tid >> 4)) & 15) * 8);

    // loop-invariant P-store bases: row=mh32+mt16+g4(+r), chunk=(sh8+nt*2+(lm>>3))^(g<<1)
    u16* pw[2][4];
#pragma unroll
    for (int mt = 0; mt < 2; ++mt)
#pragma unroll
        for (int nt = 0; nt < 4; ++nt)
            pw[mt][nt] = Ps + (mh32 + mt * 16 + g4) * 128 +
                         (((sh8 + nt * 2 + (lm >> 3)) ^ (g << 1)) * 8) + lm7;
    // loop-invariant P-read bases (A-frag), swizzle ^(((row>>2)&3)<<1)
    const int xorv = ((lm >> 2) & 3) << 1;
    const u16* prp[2][2];
#pragma unroll
    for (int mt = 0; mt < 2; ++mt)
#pragma unroll
        for (int kc = 0; kc < 2; ++kc)
            prp[mt][kc] = Ps + (mh32 + mt * 16 + lm) * 128 +
                          (((sh8 + kc * 4 + g) ^ xorv) * 8);

    const float SC2 = 0.18033688f;   // 0.125 * log2(e)
    const float MSH = -11.541560f;   // -8 * log2(e)

    auto prefetch = [&](int i, int buf) {
        u16* Kn = S_lds + buf * 8192;
        u16* Vn = S_lds + 16384 + buf * 8192;
        const u16* Kt = Kp + (long)i * 128 * 3072;
        const u16* Vg = Vp + i * 128;
#pragma unroll
        for (int j = 0; j < 4; ++j) {
            ldlds16(Kt + j * (32 * 3072) + soffK, Kn + j * 2048 + tid * 8);
            ldlds16(Vg + j * (16 * Tn) + soffV, Vn + j * 2048 + tid * 8);
        }
    };

    for (int job = 0; job < 2; ++job) {
        const int qt = job ? px : 31 - px;
        const u16* Qp = qkv + ((long)b * Tn + qt * 64) * 3072 + h * 64;

        // Q fragments straight to registers: 2 m-tiles x 2 k-halves
        short8 qa[2][2];
#pragma unroll
        for (int mt = 0; mt < 2; ++mt)
#pragma unroll
            for (int hh = 0; hh < 2; ++hh)
                qa[mt][hh] = *(const short8*)(Qp + (mh32 + mt * 16 + lm) * 3072 +
                                              hh * 32 + g * 8);

        f32x4 o_acc[2][4] = {};
        float lsum[2][4] = {};
        const int qbase = qt * 64 + mh32 + g4;

        prefetch(0, 0);
        __syncthreads();

        auto body = [&](int buf, int sbase, auto diag_c) {
            constexpr bool DIAG = decltype(diag_c)::value;
            const u16* Kc = S_lds + buf * 8192;
            const u16* Vc = S_lds + 16384 + buf * 8192;
            f32x4 s_acc[2][4];
#pragma unroll
            for (int mt = 0; mt < 2; ++mt)
#pragma unroll
                for (int nt = 0; nt < 4; ++nt)
                    s_acc[mt][nt] = (f32x4){0.f, 0.f, 0.f, 0.f};
#pragma unroll
            for (int nt = 0; nt < 4; ++nt)
#pragma unroll
                for (int hh = 0; hh < 2; ++hh) {
                    short8 kf = *(const short8*)(Kc + (sh64 + nt * 16 + lm) * 64 +
                                                 (((hh * 4 + g) ^ lm7) * 8));
                    s_acc[0][nt] = __builtin_amdgcn_mfma_f32_16x16x32_bf16(qa[0][hh], kf, s_acc[0][nt], 0, 0, 0);
                    s_acc[1][nt] = __builtin_amdgcn_mfma_f32_16x16x32_bf16(qa[1][hh], kf, s_acc[1][nt], 0, 0, 0);
                }
#pragma unroll
            for (int mt = 0; mt < 2; ++mt)
#pragma unroll
                for (int nt = 0; nt < 4; ++nt) {
                    int scol = sbase + sh64 + nt * 16 + lm;
#pragma unroll
                    for (int r = 0; r < 4; ++r) {
                        float xx = fmaf(s_acc[mt][nt][r], SC2, MSH);
                        if (DIAG && scol > qbase + mt * 16 + r) xx = -1e30f;
                        float p = exp2f(xx);
                        lsum[mt][r] += p;
                        pw[mt][nt][r * 128] = (u16)(__float_as_uint(p) >> 16);
                    }
                }
            asm volatile("s_waitcnt lgkmcnt(0)" ::: "memory");
#pragma unroll
            for (int kc = 0; kc < 2; ++kc) {
                short8 pf0 = *(const short8*)prp[0][kc];
                short8 pf1 = *(const short8*)prp[1][kc];
#pragma unroll
                for (int dt = 0; dt < 4; ++dt) {
                    short8 vf = *(const short8*)(Vc + (dt * 16 + lm) * 128 +
                                                 (((sh8 + kc * 4 + g) ^ lm) * 8));
                    o_acc[0][dt] = __builtin_amdgcn_mfma_f32_16x16x32_bf16(pf0, vf, o_acc[0][dt], 0, 0, 0);
                    o_acc[1][dt] = __builtin_amdgcn_mfma_f32_16x16x32_bf16(pf1, vf, o_acc[1][dt], 0, 0, 0);
                }
            }
        };

        const int n = (qt >> 1) + 1;     // 128-col iterations; last is DIAG
        if (n == 1) {
            body(0, 0, TrueT{});
        } else {
            int i = 0;
            for (; i + 2 <= n - 1; i += 2) {
                prefetch(i + 1, 1); body(0, i * 128, FalseT{}); __syncthreads();
                prefetch(i + 2, 0); body(1, (i + 1) * 128, FalseT{}); __syncthreads();
            }
            if (i == n - 2) {
                prefetch(n - 1, 1); body(0, i * 128, FalseT{}); __syncthreads();
                body(1, (n - 1) * 128, TrueT{});
            } else {  // i == n-1
                body(0, i * 128, TrueT{});
            }
        }

        // lsum: reduce over the 16 lanes of each row group
#pragma unroll
        for (int mt = 0; mt < 2; ++mt)
#pragma unroll
            for (int r = 0; r < 4; ++r) {
#pragma unroll
                for (int off = 1; off < 16; off <<= 1)
                    lsum[mt][r] += __shfl_xor(lsum[mt][r], off, 64);
            }

        // cross-sh reduce in LDS (overlay on Ks region), normalize, write Y
        __syncthreads();
        f32x4* redv = (f32x4*)S_lds;             // 16 KB
        float* redl = (float*)(S_lds + 8192);    // 64 floats

        if (sh == 1) {
#pragma unroll
            for (int mt = 0; mt < 2; ++mt)
#pragma unroll
                for (int dt = 0; dt < 4; ++dt)
                    redv[(mh * 64 + l) * 8 + mt * 4 + dt] = o_acc[mt][dt];
#pragma unroll
            for (int mt = 0; mt < 2; ++mt)
#pragma unroll
                for (int r = 0; r < 4; ++r)
                    if (lm == mt * 4 + r)
                        redl[mh32 + mt * 16 + g4 + r] = lsum[mt][r];
        }
        __syncthreads();
        if (sh == 0) {
#pragma unroll
            for (int mt = 0; mt < 2; ++mt) {
#pragma unroll
                for (int dt = 0; dt < 4; ++dt)
                    o_acc[mt][dt] += redv[(mh * 64 + l) * 8 + mt * 4 + dt];
#pragma unroll
                for (int r = 0; r < 4; ++r) {
                    float total = lsum[mt][r] + redl[mh32 + mt * 16 + g4 + r];
                    float inv = 1.0f / total;
                    int t = qt * 64 + mh32 + mt * 16 + g4 + r;
                    long base = ((long)b * Tn + t) * Cn + h * HDn;
#pragma unroll
                    for (int dt = 0; dt < 4; ++dt)
                        Y[base + dt * 16 + lm] = f2bf(o_acc[mt][dt][r] * inv);
                }
            }
        }
        __syncthreads();   // epilogue LDS reads done before next job restages
    }
}

extern "C" void kernel_launch(void* const* d_in, const int* in_sizes, int n_in,
                              void* d_out, int out_size, void* d_ws, size_t ws_size,
                              hipStream_t stream) {
    const float* x    = (const float*)d_in[0];
    const float* Wqkv = (const float*)d_in[1];
    const float* bqkv = (const float*)d_in[2];
    const float* Wo   = (const float*)d_in[3];
    const float* bo   = (const float*)d_in[4];
    float* out = (float*)d_out;

    u16* xb    = (u16*)d_ws;          // 4M u16 : x bf16
    u16* wqkvt = xb + 4194304;        // 3M : Wqkv^T
    u16* wot   = wqkvt + 3145728;     // 1M : Wo^T
    u16* qkvb  = wot + 1048576;       // 12M : qkv [b,t,3C] bf16
    u16* vtb   = qkvb + 12582912;     // 4M : V^T [b,h,d,t]
    u16* yb    = vtb + 4194304;       // 4M : attn out [b,t,c]

    cvt_bf16<<<4096, 256, 0, stream>>>(x, xb, 1048576);
    transpose_cvt<<<dim3(48, 16), 256, 0, stream>>>(Wqkv, wqkvt, 1024, 3072);
    transpose_cvt<<<dim3(16, 16), 256, 0, stream>>>(Wo, wot, 1024, 1024);
    gemm_bt<0><<<dim3(32, 24), 256, 0, stream>>>(xb, wqkvt, bqkv, qkvb, nullptr,
                                                 4096, 3072, 1024);
    transpose_v<<<dim3(32, 32), 256, 0, stream>>>(qkvb, vtb);
    attn<<<dim3(16, 32), 256, 0, stream>>>(qkvb, vtb, yb);
    gemm_bt<1><<<dim3(32, 8), 256, 0, stream>>>(yb, wot, bo, nullptr, out,
                                                4096, 1024, 1024);
}